// Round 1
// baseline (867.070 us; speedup 1.0000x reference)
//
#include <hip/hip_runtime.h>
#include <math.h>

#define NN   50000
#define EE   1600000
#define ETOT (EE + NN)
#define HID  128
#define INF_ 64
#define OUTF 64

__device__ __forceinline__ float gelu_tanh(float x) {
    float x3 = x * x * x;
    float u  = 0.7978845608028654f * (x + 0.044715f * x3);
    return 0.5f * x * (1.0f + tanhf(u));
}

// ---------------- CSR build ----------------

__global__ void k_init_count(int* cnt) {
    int i = blockIdx.x * 256 + threadIdx.x;
    if (i < NN) cnt[i] = 1;  // self-loop
}

__global__ void k_count(const int* __restrict__ ei, int* cnt) {
    int i = blockIdx.x * 256 + threadIdx.x;
    if (i < EE) atomicAdd(&cnt[ei[EE + i]], 1);
}

__global__ void k_scan1(const int* __restrict__ cnt, int* bsums) {
    __shared__ int s[256];
    int t = threadIdx.x;
    int i = blockIdx.x * 256 + t;
    s[t] = (i < NN) ? cnt[i] : 0;
    __syncthreads();
    for (int d = 128; d > 0; d >>= 1) {
        if (t < d) s[t] += s[t + d];
        __syncthreads();
    }
    if (t == 0) bsums[blockIdx.x] = s[0];
}

__global__ void k_scan2(int* bsums, int* off, int nb) {
    int run = 0;
    for (int b = 0; b < nb; ++b) { int v = bsums[b]; bsums[b] = run; run += v; }
    off[NN] = run;  // == ETOT
}

__global__ void k_scan3(const int* __restrict__ cnt, const int* __restrict__ bsums,
                        int* off, int* cur) {
    __shared__ int s[256];
    int t = threadIdx.x;
    int i = blockIdx.x * 256 + t;
    int v = (i < NN) ? cnt[i] : 0;
    s[t] = v;
    __syncthreads();
    for (int d = 1; d < 256; d <<= 1) {
        int x = 0;
        if (t >= d) x = s[t - d];
        __syncthreads();
        if (t >= d) s[t] += x;
        __syncthreads();
    }
    if (i < NN) {
        int o = bsums[blockIdx.x] + s[t] - v;  // exclusive scan
        off[i] = o;
        cur[i] = o;
    }
}

__global__ void k_scatter(const int* __restrict__ ei, int* cur, int* __restrict__ csr) {
    int i = blockIdx.x * 256 + threadIdx.x;
    if (i >= ETOT) return;
    int s, d;
    if (i < EE) { s = ei[i]; d = ei[EE + i]; }
    else        { s = d = i - EE; }          // self loops
    int pos = atomicAdd(&cur[d], 1);
    csr[pos] = s;
}

// ---------------- input linear: h0 = x @ w_in + b_in ----------------

__global__ __launch_bounds__(128) void k_in(const float* __restrict__ x,
                                            const float* __restrict__ w,
                                            const float* __restrict__ b,
                                            float* __restrict__ h0) {
    __shared__ float xr[INF_];
    int n = blockIdx.x, t = threadIdx.x;
    if (t < INF_) xr[t] = x[n * INF_ + t];
    __syncthreads();
    float acc = b[t];
    #pragma unroll
    for (int k = 0; k < INF_; ++k) acc = fmaf(xr[k], w[k * HID + t], acc);
    h0[n * HID + t] = acc;
}

// ------- fused LN + GELU + hW = h @ W + head scores (e_src, e_dst) -------

__global__ __launch_bounds__(128) void k_feat(const float* __restrict__ hin,
                                              const float* __restrict__ g,
                                              const float* __restrict__ be,
                                              const float* __restrict__ W,
                                              const float* __restrict__ asrc,
                                              const float* __restrict__ adst,
                                              float* __restrict__ hW,
                                              float* __restrict__ esrc,
                                              float* __restrict__ edst) {
    __shared__ float r1[128], r2[128], hrow[128];
    int n = blockIdx.x, t = threadIdx.x;
    float v = hin[n * HID + t];
    r1[t] = v; r2[t] = v * v;
    __syncthreads();
    for (int s = 64; s > 0; s >>= 1) {
        if (t < s) { r1[t] += r1[t + s]; r2[t] += r2[t + s]; }
        __syncthreads();
    }
    float mu  = r1[0] * (1.0f / 128.0f);
    float var = r2[0] * (1.0f / 128.0f) - mu * mu;
    float rs  = rsqrtf(var + 1e-5f);
    float y   = (v - mu) * rs * g[t] + be[t];
    float hx  = gelu_tanh(y);
    __syncthreads();          // r1[0]/r2[0] reads done before reuse of LDS
    hrow[t] = hx;
    __syncthreads();
    float acc = 0.f;
    #pragma unroll 8
    for (int k = 0; k < HID; ++k) acc = fmaf(hrow[k], W[k * HID + t], acc);
    hW[n * HID + t] = acc;
    // per-head scores: head = t>>5, d = t&31; a_* flat layout matches j = h*32+d
    r1[t] = acc * asrc[t];
    r2[t] = acc * adst[t];
    __syncthreads();
    for (int s = 16; s > 0; s >>= 1) {
        if ((t & 31) < s) { r1[t] += r1[t + s]; r2[t] += r2[t + s]; }
        __syncthreads();
    }
    if ((t & 31) == 0) {
        esrc[n * 4 + (t >> 5)] = r1[t];
        edst[n * 4 + (t >> 5)] = r2[t];
    }
}

// ------- GAT softmax-aggregate per destination node -------

__global__ __launch_bounds__(128) void k_gat(const float* __restrict__ hW,
                                             const float* __restrict__ esrc,
                                             const float* __restrict__ edst,
                                             const int* __restrict__ off,
                                             const int* __restrict__ csr,
                                             const float* __restrict__ bg,
                                             float* __restrict__ out) {
    __shared__ float red[128];
    __shared__ float wL[128];
    __shared__ int   sIdx[32];
    __shared__ float eD[4], mh[4], dnm[4];
    int n = blockIdx.x, t = threadIdx.x;
    int o0 = off[n], o1 = off[n + 1];
    int deg = o1 - o0;
    if (t < 4) eD[t] = edst[n * 4 + t];
    __syncthreads();
    int hh = t & 3;    // head for scoring phases (keeps e_src gathers 16B-coalesced)
    int el = t >> 2;   // edge slot within a 32-edge chunk
    float myED = eD[hh];

    // phase 1: per-head running max of leaky-relu scores
    float mx = -INFINITY;
    for (int base = 0; base < deg; base += 32) {
        int i = base + el;
        if (i < deg) {
            int s = csr[o0 + i];
            float e = esrc[s * 4 + hh] + myED;
            e = (e > 0.f) ? e : 0.2f * e;
            mx = fmaxf(mx, e);
        }
    }
    red[t] = mx;
    __syncthreads();
    for (int s = 64; s >= 4; s >>= 1) {   // strides all %4==0: preserves t&3 classes
        if (t < s) red[t] = fmaxf(red[t], red[t + s]);
        __syncthreads();
    }
    if (t < 4) mh[t] = red[t];
    __syncthreads();
    float myM = mh[hh];

    // phase 2: chunked exp-weights + aggregation; denom accumulated, divided at end
    float acc = 0.f, dpart = 0.f;
    int headj = t >> 5;   // head of this output column j = t
    for (int base = 0; base < deg; base += 32) {
        int nk = min(32, deg - base);
        __syncthreads();  // protect wL/sIdx from previous chunk's consumers
        if (el < nk) {
            int s = csr[o0 + base + el];
            if (hh == 0) sIdx[el] = s;
            float e = esrc[s * 4 + hh] + myED;
            e = (e > 0.f) ? e : 0.2f * e;
            float w = __expf(e - myM);
            wL[el * 4 + hh] = w;
            dpart += w;
        }
        __syncthreads();
        for (int e2 = 0; e2 < nk; ++e2) {
            acc = fmaf(wL[e2 * 4 + headj], hW[sIdx[e2] * HID + t], acc);
        }
    }
    __syncthreads();
    red[t] = dpart;
    __syncthreads();
    for (int s = 64; s >= 4; s >>= 1) {
        if (t < s) red[t] += red[t + s];
        __syncthreads();
    }
    if (t < 4) dnm[t] = red[t];
    __syncthreads();
    out[n * HID + t] = acc / dnm[headj] + bg[t];
}

// ---------------- output linear ----------------

__global__ __launch_bounds__(64) void k_out(const float* __restrict__ h,
                                            const float* __restrict__ w,
                                            const float* __restrict__ b,
                                            float* __restrict__ out) {
    __shared__ float row[HID];
    int n = blockIdx.x, t = threadIdx.x;
    row[t]      = h[n * HID + t];
    row[t + 64] = h[n * HID + t + 64];
    __syncthreads();
    float acc = b[t];
    #pragma unroll 8
    for (int k = 0; k < HID; ++k) acc = fmaf(row[k], w[k * OUTF + t], acc);
    out[n * OUTF + t] = acc;
}

extern "C" void kernel_launch(void* const* d_in, const int* in_sizes, int n_in,
                              void* d_out, int out_size, void* d_ws, size_t ws_size,
                              hipStream_t stream) {
    const float* x    = (const float*)d_in[0];
    const int*   ei   = (const int*)  d_in[1];   // [2, E] int32
    const float* w_in = (const float*)d_in[2];
    const float* b_in = (const float*)d_in[3];
    const float* g1   = (const float*)d_in[4];
    const float* be1  = (const float*)d_in[5];
    const float* W1   = (const float*)d_in[6];
    const float* as1  = (const float*)d_in[7];
    const float* ad1  = (const float*)d_in[8];
    const float* bg1  = (const float*)d_in[9];
    const float* g2   = (const float*)d_in[10];
    const float* be2  = (const float*)d_in[11];
    const float* W2   = (const float*)d_in[12];
    const float* as2  = (const float*)d_in[13];
    const float* ad2  = (const float*)d_in[14];
    const float* bg2  = (const float*)d_in[15];
    const float* w_o  = (const float*)d_in[16];
    const float* b_o  = (const float*)d_in[17];
    float* out = (float*)d_out;

    char* p = (char*)d_ws;
    auto take = [&](size_t bytes) {
        void* r = p;
        p += (bytes + 255) & ~(size_t)255;
        return r;
    };
    float* h0   = (float*)take((size_t)NN * HID * 4);
    float* hW   = (float*)take((size_t)NN * HID * 4);
    float* gout = (float*)take((size_t)NN * HID * 4);
    float* esrc = (float*)take((size_t)NN * 4 * 4);
    float* edst = (float*)take((size_t)NN * 4 * 4);
    int*   cnt  = (int*)take((size_t)NN * 4);
    int*   off  = (int*)take((size_t)(NN + 1) * 4);
    int*   cur  = (int*)take((size_t)NN * 4);
    int*   bsum = (int*)take(4096);
    int*   csr  = (int*)take((size_t)ETOT * 4);

    int nb = (NN + 255) / 256;  // 196 blocks
    k_init_count<<<nb, 256, 0, stream>>>(cnt);
    k_count<<<(EE + 255) / 256, 256, 0, stream>>>(ei, cnt);
    k_scan1<<<nb, 256, 0, stream>>>(cnt, bsum);
    k_scan2<<<1, 1, 0, stream>>>(bsum, off, nb);
    k_scan3<<<nb, 256, 0, stream>>>(cnt, bsum, off, cur);
    k_scatter<<<(ETOT + 255) / 256, 256, 0, stream>>>(ei, cur, csr);

    k_in  <<<NN, 128, 0, stream>>>(x, w_in, b_in, h0);
    k_feat<<<NN, 128, 0, stream>>>(h0,   g1, be1, W1, as1, ad1, hW, esrc, edst);
    k_gat <<<NN, 128, 0, stream>>>(hW, esrc, edst, off, csr, bg1, gout);
    k_feat<<<NN, 128, 0, stream>>>(gout, g2, be2, W2, as2, ad2, hW, esrc, edst);
    k_gat <<<NN, 128, 0, stream>>>(hW, esrc, edst, off, csr, bg2, h0);
    k_out <<<NN, 64, 0, stream>>>(h0, w_o, b_o, out);
}

// Round 2
// 766.952 us; speedup vs baseline: 1.1305x; 1.1305x over previous
//
#include <hip/hip_runtime.h>
#include <hip/hip_bf16.h>
#include <math.h>

#define NN   50000
#define EE   1600000
#define ETOT (EE + NN)
#define HID  128
#define INF_ 64
#define OUTF 64

// bucketed CSR build
#define NBK  1024   // buckets (contiguous dst ranges)
#define NPB  49     // nodes per bucket (1024*49 = 50176 >= NN)
#define CAP  3072   // per-bucket capacity; mean ~1617, 1.9x headroom (overflow p ~ e^-188)

__device__ __forceinline__ float gelu_tanh(float x) {
    float x3 = x * x * x;
    float u  = 0.7978845608028654f * (x + 0.044715f * x3);
    return 0.5f * x * (1.0f + tanhf(u));
}

// ---------------- CSR build (bucketed counting sort) ----------------

__global__ void k_zero(int* bcur) {
    int i = blockIdx.x * 256 + threadIdx.x;
    if (i < NBK) bcur[i] = 0;
}

// pass 1: bin edges into per-bucket streams, packed (src<<6)|(dst - bucket_node0)
__global__ void k_bucket(const int* __restrict__ ei, int* bcur, int* __restrict__ tmp) {
    int i = blockIdx.x * 256 + threadIdx.x;
    if (i >= ETOT) return;
    int s, d;
    if (i < EE) { s = ei[i]; d = ei[EE + i]; }
    else        { s = d = i - EE; }          // self loops
    int b   = d / NPB;
    int pos = atomicAdd(&bcur[b], 1);
    if (pos < CAP) tmp[b * CAP + pos] = (s << 6) | (d - b * NPB);
}

// exclusive scan of 1024 bucket sizes (one block)
__global__ __launch_bounds__(1024) void k_bscan(const int* __restrict__ bcur,
                                                int* __restrict__ bstart,
                                                int* __restrict__ off) {
    __shared__ int s[NBK];
    int t = threadIdx.x;
    int v0 = bcur[t];
    s[t] = v0;
    __syncthreads();
    for (int d = 1; d < NBK; d <<= 1) {
        int v = (t >= d) ? s[t - d] : 0;
        __syncthreads();
        s[t] += v;
        __syncthreads();
    }
    bstart[t] = s[t] - v0;     // exclusive
    if (t == 0) off[NN] = ETOT;
}

// pass 2: one block per bucket — stage in LDS, count, scan, scatter; writes off[] too
__global__ __launch_bounds__(256) void k_bucket2csr(const int* __restrict__ tmp,
                                                    const int* __restrict__ bcur,
                                                    const int* __restrict__ bstart,
                                                    int* __restrict__ off,
                                                    int* __restrict__ csr) {
    __shared__ int sE[CAP];
    __shared__ int lcnt[NPB];
    __shared__ int loff[NPB];
    int b = blockIdx.x, t = threadIdx.x;
    int n0    = b * NPB;
    int bsize = min(bcur[b], CAP);
    int base  = bstart[b];
    if (t < NPB) lcnt[t] = 0;
    for (int i = t; i < bsize; i += 256) sE[i] = tmp[b * CAP + i];
    __syncthreads();
    for (int i = t; i < bsize; i += 256) atomicAdd(&lcnt[sE[i] & 63], 1);
    __syncthreads();
    if (t == 0) {
        int run = 0;
        for (int j = 0; j < NPB; ++j) { loff[j] = run; run += lcnt[j]; }
    }
    __syncthreads();
    if (t < NPB) {
        if (n0 + t < NN) off[n0 + t] = base + loff[t];
        lcnt[t] = loff[t];            // reuse as cursor
    }
    __syncthreads();
    for (int i = t; i < bsize; i += 256) {
        int v   = sE[i];
        int pos = base + atomicAdd(&lcnt[v & 63], 1);
        csr[pos] = v >> 6;
    }
}

// ---------------- input linear: h0 = x @ w_in + b_in (8 nodes/block) ----------------

__global__ __launch_bounds__(128) void k_in(const float* __restrict__ x,
                                            const float* __restrict__ w,
                                            const float* __restrict__ b,
                                            float* __restrict__ h0) {
    __shared__ __align__(16) float xr[8][INF_];
    int n0 = blockIdx.x * 8, t = threadIdx.x;
    for (int i = t; i < 8 * INF_; i += 128) xr[i >> 6][i & 63] = x[n0 * INF_ + i];
    __syncthreads();
    float acc[8];
    float bb = b[t];
    #pragma unroll
    for (int r = 0; r < 8; ++r) acc[r] = bb;
    const float4* h4 = reinterpret_cast<const float4*>(&xr[0][0]);
    for (int k4 = 0; k4 < INF_ / 4; ++k4) {
        int k = k4 * 4;
        float w0 = w[(k + 0) * HID + t];
        float w1 = w[(k + 1) * HID + t];
        float w2 = w[(k + 2) * HID + t];
        float w3 = w[(k + 3) * HID + t];
        #pragma unroll
        for (int r = 0; r < 8; ++r) {
            float4 hv = h4[r * (INF_ / 4) + k4];
            acc[r] = fmaf(hv.x, w0, fmaf(hv.y, w1, fmaf(hv.z, w2, fmaf(hv.w, w3, acc[r]))));
        }
    }
    #pragma unroll
    for (int r = 0; r < 8; ++r) h0[(n0 + r) * HID + t] = acc[r];
}

// ------- fused LN + GELU + hW = h @ W (bf16 out) + head scores (8 nodes/block) -------

__global__ __launch_bounds__(128) void k_feat(const float* __restrict__ hin,
                                              const float* __restrict__ g,
                                              const float* __restrict__ be,
                                              const float* __restrict__ W,
                                              const float* __restrict__ asrc,
                                              const float* __restrict__ adst,
                                              __hip_bfloat16* __restrict__ hWb,
                                              float* __restrict__ esrc,
                                              float* __restrict__ edst) {
    __shared__ __align__(16) float hrow[8][HID];
    int n0 = blockIdx.x * 8, t = threadIdx.x;
    for (int i = t; i < 8 * HID; i += 128) hrow[i >> 7][i & 127] = hin[n0 * HID + i];
    __syncthreads();

    // LN stats: node = t>>4 (8 nodes), lane = t&15, width-16 shuffle reduce
    int node = t >> 4, lane = t & 15;
    float s1 = 0.f, s2 = 0.f;
    #pragma unroll
    for (int j = 0; j < 8; ++j) {
        float v = hrow[node][lane + 16 * j];
        s1 += v; s2 += v * v;
    }
    #pragma unroll
    for (int m = 1; m < 16; m <<= 1) {
        s1 += __shfl_xor(s1, m, 16);
        s2 += __shfl_xor(s2, m, 16);
    }
    float mu  = s1 * (1.0f / 128.0f);
    float var = s2 * (1.0f / 128.0f) - mu * mu;
    float rs  = rsqrtf(var + 1e-5f);
    #pragma unroll
    for (int j = 0; j < 8; ++j) {
        int col = lane + 16 * j;
        float v = hrow[node][col];
        float y = (v - mu) * rs * g[col] + be[col];
        hrow[node][col] = gelu_tanh(y);   // same 16 lanes wrote/read this row: wave-sync safe
    }
    __syncthreads();

    // GEMM: col t, 8 nodes
    float acc[8] = {0.f, 0.f, 0.f, 0.f, 0.f, 0.f, 0.f, 0.f};
    const float4* h4 = reinterpret_cast<const float4*>(&hrow[0][0]);
    for (int k4 = 0; k4 < HID / 4; ++k4) {
        int k = k4 * 4;
        float w0 = W[(k + 0) * HID + t];
        float w1 = W[(k + 1) * HID + t];
        float w2 = W[(k + 2) * HID + t];
        float w3 = W[(k + 3) * HID + t];
        #pragma unroll
        for (int r = 0; r < 8; ++r) {
            float4 hv = h4[r * (HID / 4) + k4];
            acc[r] = fmaf(hv.x, w0, fmaf(hv.y, w1, fmaf(hv.z, w2, fmaf(hv.w, w3, acc[r]))));
        }
    }
    float as = asrc[t], ad = adst[t];
    #pragma unroll
    for (int r = 0; r < 8; ++r) {
        hWb[(n0 + r) * HID + t] = __float2bfloat16(acc[r]);
        // head scores: reduce acc*a over each 32-col head group
        float v1 = acc[r] * as, v2 = acc[r] * ad;
        #pragma unroll
        for (int m = 1; m < 32; m <<= 1) {
            v1 += __shfl_xor(v1, m, 32);
            v2 += __shfl_xor(v2, m, 32);
        }
        if ((t & 31) == 0) {
            esrc[(n0 + r) * 4 + (t >> 5)] = v1;
            edst[(n0 + r) * 4 + (t >> 5)] = v2;
        }
    }
}

// ------- GAT softmax-aggregate per destination node (no max pass; scores are O(1)) -------

__global__ __launch_bounds__(128) void k_gat(const __hip_bfloat16* __restrict__ hWb,
                                             const float* __restrict__ esrc,
                                             const float* __restrict__ edst,
                                             const int* __restrict__ off,
                                             const int* __restrict__ csr,
                                             const float* __restrict__ bg,
                                             float* __restrict__ out) {
    __shared__ float red[128];
    __shared__ float wL[128];
    __shared__ int   sIdx[32];
    __shared__ float eD[4], dnm[4];
    int n = blockIdx.x, t = threadIdx.x;
    int o0 = off[n], deg = off[n + 1] - o0;
    if (t < 4) eD[t] = edst[n * 4 + t];
    __syncthreads();
    int hh = t & 3;    // head for scoring (16B-coalesced e_src gathers)
    int el = t >> 2;   // edge slot in 32-edge chunk
    float myED = eD[hh];

    float acc = 0.f, dpart = 0.f;
    int headj = t >> 5;   // head of output column t
    for (int base = 0; base < deg; base += 32) {
        int nk = min(32, deg - base);
        __syncthreads();
        if (el < nk) {
            int s = csr[o0 + base + el];
            if (hh == 0) sIdx[el] = s;
            float e = esrc[s * 4 + hh] + myED;
            e = (e > 0.f) ? e : 0.2f * e;
            float w = __expf(e);          // no max-subtraction: |e| <~ 2, exactly safe
            wL[el * 4 + hh] = w;
            dpart += w;
        }
        __syncthreads();
        for (int e2 = 0; e2 < nk; ++e2) {
            float hv = __bfloat162float(hWb[sIdx[e2] * HID + t]);
            acc = fmaf(wL[e2 * 4 + headj], hv, acc);
        }
    }
    __syncthreads();
    red[t] = dpart;
    __syncthreads();
    for (int s = 64; s >= 4; s >>= 1) {   // strides %4==0: preserves t&3 classes
        if (t < s) red[t] += red[t + s];
        __syncthreads();
    }
    if (t < 4) dnm[t] = red[t];
    __syncthreads();
    out[n * HID + t] = acc / dnm[headj] + bg[t];
}

// ---------------- output linear (8 nodes/block) ----------------

__global__ __launch_bounds__(64) void k_out(const float* __restrict__ h,
                                            const float* __restrict__ w,
                                            const float* __restrict__ b,
                                            float* __restrict__ out) {
    __shared__ __align__(16) float hr[8][HID];
    int n0 = blockIdx.x * 8, t = threadIdx.x;
    for (int i = t; i < 8 * HID; i += 64) hr[i >> 7][i & 127] = h[n0 * HID + i];
    __syncthreads();
    float acc[8];
    float bb = b[t];
    #pragma unroll
    for (int r = 0; r < 8; ++r) acc[r] = bb;
    const float4* h4 = reinterpret_cast<const float4*>(&hr[0][0]);
    for (int k4 = 0; k4 < HID / 4; ++k4) {
        int k = k4 * 4;
        float w0 = w[(k + 0) * OUTF + t];
        float w1 = w[(k + 1) * OUTF + t];
        float w2 = w[(k + 2) * OUTF + t];
        float w3 = w[(k + 3) * OUTF + t];
        #pragma unroll
        for (int r = 0; r < 8; ++r) {
            float4 hv = h4[r * (HID / 4) + k4];
            acc[r] = fmaf(hv.x, w0, fmaf(hv.y, w1, fmaf(hv.z, w2, fmaf(hv.w, w3, acc[r]))));
        }
    }
    #pragma unroll
    for (int r = 0; r < 8; ++r) out[(n0 + r) * OUTF + t] = acc[r];
}

extern "C" void kernel_launch(void* const* d_in, const int* in_sizes, int n_in,
                              void* d_out, int out_size, void* d_ws, size_t ws_size,
                              hipStream_t stream) {
    const float* x    = (const float*)d_in[0];
    const int*   ei   = (const int*)  d_in[1];   // [2, E] int32
    const float* w_in = (const float*)d_in[2];
    const float* b_in = (const float*)d_in[3];
    const float* g1   = (const float*)d_in[4];
    const float* be1  = (const float*)d_in[5];
    const float* W1   = (const float*)d_in[6];
    const float* as1  = (const float*)d_in[7];
    const float* ad1  = (const float*)d_in[8];
    const float* bg1  = (const float*)d_in[9];
    const float* g2   = (const float*)d_in[10];
    const float* be2  = (const float*)d_in[11];
    const float* W2   = (const float*)d_in[12];
    const float* as2  = (const float*)d_in[13];
    const float* ad2  = (const float*)d_in[14];
    const float* bg2  = (const float*)d_in[15];
    const float* w_o  = (const float*)d_in[16];
    const float* b_o  = (const float*)d_in[17];
    float* out = (float*)d_out;

    char* p = (char*)d_ws;
    auto take = [&](size_t bytes) {
        void* r = p;
        p += (bytes + 255) & ~(size_t)255;
        return r;
    };
    float*          h0    = (float*)take((size_t)NN * HID * 4);
    float*          gout  = (float*)take((size_t)NN * HID * 4);
    __hip_bfloat16* hWb   = (__hip_bfloat16*)take((size_t)NN * HID * 2);
    float*          esrc  = (float*)take((size_t)NN * 4 * 4);
    float*          edst  = (float*)take((size_t)NN * 4 * 4);
    int*            off   = (int*)take((size_t)(NN + 1) * 4);
    int*            csr   = (int*)take((size_t)ETOT * 4);
    int*            tmp   = (int*)take((size_t)NBK * CAP * 4);
    int*            bcur  = (int*)take((size_t)NBK * 4);
    int*            bstart= (int*)take((size_t)NBK * 4);

    k_zero      <<<(NBK + 255) / 256, 256, 0, stream>>>(bcur);
    k_bucket    <<<(ETOT + 255) / 256, 256, 0, stream>>>(ei, bcur, tmp);
    k_bscan     <<<1, NBK, 0, stream>>>(bcur, bstart, off);
    k_bucket2csr<<<NBK, 256, 0, stream>>>(tmp, bcur, bstart, off, csr);

    k_in  <<<NN / 8, 128, 0, stream>>>(x, w_in, b_in, h0);
    k_feat<<<NN / 8, 128, 0, stream>>>(h0,   g1, be1, W1, as1, ad1, hWb, esrc, edst);
    k_gat <<<NN, 128, 0, stream>>>(hWb, esrc, edst, off, csr, bg1, gout);
    k_feat<<<NN / 8, 128, 0, stream>>>(gout, g2, be2, W2, as2, ad2, hWb, esrc, edst);
    k_gat <<<NN, 128, 0, stream>>>(hWb, esrc, edst, off, csr, bg2, h0);
    k_out <<<NN / 8, 64, 0, stream>>>(h0, w_o, b_o, out);
}

// Round 3
// 521.458 us; speedup vs baseline: 1.6628x; 1.4708x over previous
//
#include <hip/hip_runtime.h>
#include <hip/hip_bf16.h>
#include <math.h>

#define NN   50000
#define EE   1600000
#define ETOT (EE + NN)
#define HID  128
#define INF_ 64
#define OUTF 64

// bucketed CSR build
#define NBK  1024   // buckets (contiguous dst ranges)
#define NPB  49     // nodes per bucket (1024*49 = 50176 >= NN)
#define CAP  3072   // per-bucket capacity; mean ~1617, 1.9x headroom
#define ABLK 256    // aggregation blocks for k_bucket

__device__ __forceinline__ float gelu_tanh(float x) {
    float x3 = x * x * x;
    float u  = 0.7978845608028654f * (x + 0.044715f * x3);
    return 0.5f * x * (1.0f + tanhf(u));
}

// ---------------- CSR build (bucketed counting sort) ----------------

__global__ void k_zero(int* bcur) {
    int i = blockIdx.x * 256 + threadIdx.x;
    if (i < NBK) bcur[i] = 0;
}

// pass 1: bin edges into per-bucket streams, packed (src<<6)|(dst - bucket_node0).
// Block-aggregated: LDS histogram -> one global atomic per (block,bucket) to
// reserve a contiguous range -> LDS-cursor placement. Cuts 1.65M contended
// global atomics (1611/address) down to ~262K range-reservations (256/address).
__global__ __launch_bounds__(1024) void k_bucket(const int* __restrict__ ei,
                                                 int* bcur, int* __restrict__ tmp) {
    __shared__ int hist[NBK];
    int t = threadIdx.x;
    for (int j = t; j < NBK; j += 1024) hist[j] = 0;
    const int chunk = (ETOT + ABLK - 1) / ABLK;
    int lo = blockIdx.x * chunk;
    int hi = min(lo + chunk, ETOT);
    __syncthreads();
    for (int i = lo + t; i < hi; i += 1024) {
        int d = (i < EE) ? ei[EE + i] : i - EE;
        atomicAdd(&hist[d / NPB], 1);
    }
    __syncthreads();
    for (int j = t; j < NBK; j += 1024) {
        int c = hist[j];
        int base = (c > 0) ? atomicAdd(&bcur[j], c) : 0;
        hist[j] = base;             // reuse as cursor (global offset in bucket stream)
    }
    __syncthreads();
    for (int i = lo + t; i < hi; i += 1024) {
        int s, d;
        if (i < EE) { s = ei[i]; d = ei[EE + i]; }
        else        { s = d = i - EE; }          // self loops
        int b   = d / NPB;
        int pos = atomicAdd(&hist[b], 1);
        if (pos < CAP) tmp[b * CAP + pos] = (s << 6) | (d - b * NPB);
    }
}

// exclusive scan of 1024 bucket sizes (one block)
__global__ __launch_bounds__(1024) void k_bscan(const int* __restrict__ bcur,
                                                int* __restrict__ bstart,
                                                int* __restrict__ off) {
    __shared__ int s[NBK];
    int t = threadIdx.x;
    int v0 = bcur[t];
    s[t] = v0;
    __syncthreads();
    for (int d = 1; d < NBK; d <<= 1) {
        int v = (t >= d) ? s[t - d] : 0;
        __syncthreads();
        s[t] += v;
        __syncthreads();
    }
    bstart[t] = s[t] - v0;     // exclusive
    if (t == 0) off[NN] = ETOT;
}

// pass 2: one block per bucket — stage in LDS, count, scan, scatter; writes off[] too
__global__ __launch_bounds__(256) void k_bucket2csr(const int* __restrict__ tmp,
                                                    const int* __restrict__ bcur,
                                                    const int* __restrict__ bstart,
                                                    int* __restrict__ off,
                                                    int* __restrict__ csr) {
    __shared__ int sE[CAP];
    __shared__ int lcnt[NPB];
    __shared__ int loff[NPB];
    int b = blockIdx.x, t = threadIdx.x;
    int n0    = b * NPB;
    int bsize = min(bcur[b], CAP);
    int base  = bstart[b];
    if (t < NPB) lcnt[t] = 0;
    for (int i = t; i < bsize; i += 256) sE[i] = tmp[b * CAP + i];
    __syncthreads();
    for (int i = t; i < bsize; i += 256) atomicAdd(&lcnt[sE[i] & 63], 1);
    __syncthreads();
    if (t == 0) {
        int run = 0;
        for (int j = 0; j < NPB; ++j) { loff[j] = run; run += lcnt[j]; }
    }
    __syncthreads();
    if (t < NPB) {
        if (n0 + t < NN) off[n0 + t] = base + loff[t];
        lcnt[t] = loff[t];            // reuse as cursor
    }
    __syncthreads();
    for (int i = t; i < bsize; i += 256) {
        int v   = sE[i];
        int pos = base + atomicAdd(&lcnt[v & 63], 1);
        csr[pos] = v >> 6;
    }
}

// ---------------- input linear: h0 = x @ w_in + b_in (8 nodes/block) ----------------

__global__ __launch_bounds__(128) void k_in(const float* __restrict__ x,
                                            const float* __restrict__ w,
                                            const float* __restrict__ b,
                                            float* __restrict__ h0) {
    __shared__ __align__(16) float xr[8][INF_];
    int n0 = blockIdx.x * 8, t = threadIdx.x;
    for (int i = t; i < 8 * INF_; i += 128) xr[i >> 6][i & 63] = x[n0 * INF_ + i];
    __syncthreads();
    float acc[8];
    float bb = b[t];
    #pragma unroll
    for (int r = 0; r < 8; ++r) acc[r] = bb;
    const float4* h4 = reinterpret_cast<const float4*>(&xr[0][0]);
    for (int k4 = 0; k4 < INF_ / 4; ++k4) {
        int k = k4 * 4;
        float w0 = w[(k + 0) * HID + t];
        float w1 = w[(k + 1) * HID + t];
        float w2 = w[(k + 2) * HID + t];
        float w3 = w[(k + 3) * HID + t];
        #pragma unroll
        for (int r = 0; r < 8; ++r) {
            float4 hv = h4[r * (INF_ / 4) + k4];
            acc[r] = fmaf(hv.x, w0, fmaf(hv.y, w1, fmaf(hv.z, w2, fmaf(hv.w, w3, acc[r]))));
        }
    }
    #pragma unroll
    for (int r = 0; r < 8; ++r) h0[(n0 + r) * HID + t] = acc[r];
}

// ------- fused LN + GELU + hW = h @ W (bf16 out) + head scores (8 nodes/block) -------

__global__ __launch_bounds__(128) void k_feat(const float* __restrict__ hin,
                                              const float* __restrict__ g,
                                              const float* __restrict__ be,
                                              const float* __restrict__ W,
                                              const float* __restrict__ asrc,
                                              const float* __restrict__ adst,
                                              __hip_bfloat16* __restrict__ hWb,
                                              float* __restrict__ esrc,
                                              float* __restrict__ edst) {
    __shared__ __align__(16) float hrow[8][HID];
    int n0 = blockIdx.x * 8, t = threadIdx.x;
    for (int i = t; i < 8 * HID; i += 128) hrow[i >> 7][i & 127] = hin[n0 * HID + i];
    __syncthreads();

    // LN stats: node = t>>4 (8 nodes), lane = t&15, width-16 shuffle reduce
    int node = t >> 4, lane = t & 15;
    float s1 = 0.f, s2 = 0.f;
    #pragma unroll
    for (int j = 0; j < 8; ++j) {
        float v = hrow[node][lane + 16 * j];
        s1 += v; s2 += v * v;
    }
    #pragma unroll
    for (int m = 1; m < 16; m <<= 1) {
        s1 += __shfl_xor(s1, m, 16);
        s2 += __shfl_xor(s2, m, 16);
    }
    float mu  = s1 * (1.0f / 128.0f);
    float var = s2 * (1.0f / 128.0f) - mu * mu;
    float rs  = rsqrtf(var + 1e-5f);
    #pragma unroll
    for (int j = 0; j < 8; ++j) {
        int col = lane + 16 * j;
        float v = hrow[node][col];
        float y = (v - mu) * rs * g[col] + be[col];
        hrow[node][col] = gelu_tanh(y);   // same thread wrote/reads this slot
    }
    __syncthreads();

    // GEMM: col t, 8 nodes
    float acc[8] = {0.f, 0.f, 0.f, 0.f, 0.f, 0.f, 0.f, 0.f};
    const float4* h4 = reinterpret_cast<const float4*>(&hrow[0][0]);
    for (int k4 = 0; k4 < HID / 4; ++k4) {
        int k = k4 * 4;
        float w0 = W[(k + 0) * HID + t];
        float w1 = W[(k + 1) * HID + t];
        float w2 = W[(k + 2) * HID + t];
        float w3 = W[(k + 3) * HID + t];
        #pragma unroll
        for (int r = 0; r < 8; ++r) {
            float4 hv = h4[r * (HID / 4) + k4];
            acc[r] = fmaf(hv.x, w0, fmaf(hv.y, w1, fmaf(hv.z, w2, fmaf(hv.w, w3, acc[r]))));
        }
    }
    float as = asrc[t], ad = adst[t];
    #pragma unroll
    for (int r = 0; r < 8; ++r) {
        hWb[(n0 + r) * HID + t] = __float2bfloat16(acc[r]);
        // head scores: reduce acc*a over each 32-col head group
        float v1 = acc[r] * as, v2 = acc[r] * ad;
        #pragma unroll
        for (int m = 1; m < 32; m <<= 1) {
            v1 += __shfl_xor(v1, m, 32);
            v2 += __shfl_xor(v2, m, 32);
        }
        if ((t & 31) == 0) {
            esrc[(n0 + r) * 4 + (t >> 5)] = v1;
            edst[(n0 + r) * 4 + (t >> 5)] = v2;
        }
    }
}

// ------- GAT softmax-aggregate per destination node -------
// Aggregation remapped to bf16x2: 128 threads = 2 edge-slots (r=t>>6, one per
// wave) x 64 column-pairs (c=t&63). Halves loop trips, 4B loads instead of 2B.

__global__ __launch_bounds__(128) void k_gat(const __hip_bfloat16* __restrict__ hWb,
                                             const float* __restrict__ esrc,
                                             const float* __restrict__ edst,
                                             const int* __restrict__ off,
                                             const int* __restrict__ csr,
                                             const float* __restrict__ bg,
                                             float* __restrict__ out) {
    __shared__ float red[128];
    __shared__ float wL[128];
    __shared__ int   sIdx[32];
    __shared__ float eD[4], dnm[4];
    __shared__ float2 red2[64];
    int n = blockIdx.x, t = threadIdx.x;
    int o0 = off[n], deg = off[n + 1] - o0;
    if (t < 4) eD[t] = edst[n * 4 + t];
    __syncthreads();
    int hh = t & 3;      // head for scoring phase (16B-coalesced e_src gathers)
    int el = t >> 2;     // edge slot in 32-edge chunk (scoring phase)
    float myED = eD[hh];
    int r = t >> 6;      // edge parity (wave id) for aggregation
    int c = t & 63;      // column pair -> columns 2c, 2c+1
    int headc = c >> 4;  // head of both columns (2c)>>5 == c>>4
    const __hip_bfloat162* hW2 = reinterpret_cast<const __hip_bfloat162*>(hWb);

    float2 acc = {0.f, 0.f};
    float dpart = 0.f;
    for (int base = 0; base < deg; base += 32) {
        int nk = min(32, deg - base);
        __syncthreads();
        if (el < nk) {
            int s = csr[o0 + base + el];
            if (hh == 0) sIdx[el] = s;
            float e = esrc[s * 4 + hh] + myED;
            e = (e > 0.f) ? e : 0.2f * e;
            float w = __expf(e);          // no max-subtraction: |e| <~ 2, safe in fp32
            wL[el * 4 + hh] = w;
            dpart += w;
        }
        __syncthreads();
        int half = (nk + 1) >> 1;
        for (int e2 = 0; e2 < half; ++e2) {
            int eidx = 2 * e2 + r;
            if (eidx < nk) {
                float w = wL[eidx * 4 + headc];
                __hip_bfloat162 hv = hW2[sIdx[eidx] * 64 + c];
                acc.x = fmaf(w, __bfloat162float(hv.x), acc.x);
                acc.y = fmaf(w, __bfloat162float(hv.y), acc.y);
            }
        }
    }
    __syncthreads();
    red[t] = dpart;
    __syncthreads();
    for (int s = 64; s >= 4; s >>= 1) {   // strides %4==0: preserves t&3 classes
        if (t < s) red[t] += red[t + s];
        __syncthreads();
    }
    if (t < 4) dnm[t] = red[t];
    __syncthreads();
    if (r == 1) red2[c] = acc;            // odd-edge partials over to wave 0
    __syncthreads();
    if (r == 0) {
        float2 o = red2[c];
        float inv = 1.0f / dnm[headc];
        float2 res;
        res.x = (acc.x + o.x) * inv + bg[2 * c];
        res.y = (acc.y + o.y) * inv + bg[2 * c + 1];
        reinterpret_cast<float2*>(out)[n * 64 + c] = res;
    }
}

// ---------------- output linear (8 nodes/block) ----------------

__global__ __launch_bounds__(64) void k_out(const float* __restrict__ h,
                                            const float* __restrict__ w,
                                            const float* __restrict__ b,
                                            float* __restrict__ out) {
    __shared__ __align__(16) float hr[8][HID];
    int n0 = blockIdx.x * 8, t = threadIdx.x;
    for (int i = t; i < 8 * HID; i += 64) hr[i >> 7][i & 127] = h[n0 * HID + i];
    __syncthreads();
    float acc[8];
    float bb = b[t];
    #pragma unroll
    for (int r = 0; r < 8; ++r) acc[r] = bb;
    const float4* h4 = reinterpret_cast<const float4*>(&hr[0][0]);
    for (int k4 = 0; k4 < HID / 4; ++k4) {
        int k = k4 * 4;
        float w0 = w[(k + 0) * OUTF + t];
        float w1 = w[(k + 1) * OUTF + t];
        float w2 = w[(k + 2) * OUTF + t];
        float w3 = w[(k + 3) * OUTF + t];
        #pragma unroll
        for (int r = 0; r < 8; ++r) {
            float4 hv = h4[r * (HID / 4) + k4];
            acc[r] = fmaf(hv.x, w0, fmaf(hv.y, w1, fmaf(hv.z, w2, fmaf(hv.w, w3, acc[r]))));
        }
    }
    #pragma unroll
    for (int r = 0; r < 8; ++r) out[(n0 + r) * OUTF + t] = acc[r];
}

extern "C" void kernel_launch(void* const* d_in, const int* in_sizes, int n_in,
                              void* d_out, int out_size, void* d_ws, size_t ws_size,
                              hipStream_t stream) {
    const float* x    = (const float*)d_in[0];
    const int*   ei   = (const int*)  d_in[1];   // [2, E] int32
    const float* w_in = (const float*)d_in[2];
    const float* b_in = (const float*)d_in[3];
    const float* g1   = (const float*)d_in[4];
    const float* be1  = (const float*)d_in[5];
    const float* W1   = (const float*)d_in[6];
    const float* as1  = (const float*)d_in[7];
    const float* ad1  = (const float*)d_in[8];
    const float* bg1  = (const float*)d_in[9];
    const float* g2   = (const float*)d_in[10];
    const float* be2  = (const float*)d_in[11];
    const float* W2   = (const float*)d_in[12];
    const float* as2  = (const float*)d_in[13];
    const float* ad2  = (const float*)d_in[14];
    const float* bg2  = (const float*)d_in[15];
    const float* w_o  = (const float*)d_in[16];
    const float* b_o  = (const float*)d_in[17];
    float* out = (float*)d_out;

    char* p = (char*)d_ws;
    auto take = [&](size_t bytes) {
        void* r = p;
        p += (bytes + 255) & ~(size_t)255;
        return r;
    };
    float*          h0    = (float*)take((size_t)NN * HID * 4);
    float*          gout  = (float*)take((size_t)NN * HID * 4);
    __hip_bfloat16* hWb   = (__hip_bfloat16*)take((size_t)NN * HID * 2);
    float*          esrc  = (float*)take((size_t)NN * 4 * 4);
    float*          edst  = (float*)take((size_t)NN * 4 * 4);
    int*            off   = (int*)take((size_t)(NN + 1) * 4);
    int*            csr   = (int*)take((size_t)ETOT * 4);
    int*            tmp   = (int*)take((size_t)NBK * CAP * 4);
    int*            bcur  = (int*)take((size_t)NBK * 4);
    int*            bstart= (int*)take((size_t)NBK * 4);

    k_zero      <<<(NBK + 255) / 256, 256, 0, stream>>>(bcur);
    k_bucket    <<<ABLK, 1024, 0, stream>>>(ei, bcur, tmp);
    k_bscan     <<<1, NBK, 0, stream>>>(bcur, bstart, off);
    k_bucket2csr<<<NBK, 256, 0, stream>>>(tmp, bcur, bstart, off, csr);

    k_in  <<<NN / 8, 128, 0, stream>>>(x, w_in, b_in, h0);
    k_feat<<<NN / 8, 128, 0, stream>>>(h0,   g1, be1, W1, as1, ad1, hWb, esrc, edst);
    k_gat <<<NN, 128, 0, stream>>>(hWb, esrc, edst, off, csr, bg1, gout);
    k_feat<<<NN / 8, 128, 0, stream>>>(gout, g2, be2, W2, as2, ad2, hWb, esrc, edst);
    k_gat <<<NN, 128, 0, stream>>>(hWb, esrc, edst, off, csr, bg2, h0);
    k_out <<<NN / 8, 64, 0, stream>>>(h0, w_o, b_o, out);
}

// Round 4
// 434.796 us; speedup vs baseline: 1.9942x; 1.1993x over previous
//
#include <hip/hip_runtime.h>
#include <hip/hip_bf16.h>
#include <math.h>

#define NN   50000
#define EE   1600000
#define ETOT (EE + NN)
#define HID  128
#define INF_ 64
#define OUTF 64

// bucketed CSR build
#define NBK  1024   // buckets (contiguous dst ranges)
#define NPB  49     // nodes per bucket (1024*49 = 50176 >= NN)
#define CAP  3072   // per-bucket capacity; mean ~1617, 1.9x headroom
#define ABLK 256    // aggregation blocks for k_bucket

__device__ __forceinline__ float gelu_tanh(float x) {
    float x3 = x * x * x;
    float u  = 0.7978845608028654f * (x + 0.044715f * x3);
    return 0.5f * x * (1.0f + tanhf(u));
}

// ---------------- CSR build (bucketed counting sort) ----------------

__global__ void k_zero(int* bcur) {
    int i = blockIdx.x * 256 + threadIdx.x;
    if (i < NBK) bcur[i] = 0;
}

// pass 1: bin edges into per-bucket streams, packed (src<<6)|(dst - bucket_node0).
// Block-aggregated: LDS histogram -> one global atomic per (block,bucket) to
// reserve a contiguous range -> LDS-cursor placement.
__global__ __launch_bounds__(1024) void k_bucket(const int* __restrict__ ei,
                                                 int* bcur, int* __restrict__ tmp) {
    __shared__ int hist[NBK];
    int t = threadIdx.x;
    for (int j = t; j < NBK; j += 1024) hist[j] = 0;
    const int chunk = (ETOT + ABLK - 1) / ABLK;
    int lo = blockIdx.x * chunk;
    int hi = min(lo + chunk, ETOT);
    __syncthreads();
    for (int i = lo + t; i < hi; i += 1024) {
        int d = (i < EE) ? ei[EE + i] : i - EE;
        atomicAdd(&hist[d / NPB], 1);
    }
    __syncthreads();
    for (int j = t; j < NBK; j += 1024) {
        int c = hist[j];
        int base = (c > 0) ? atomicAdd(&bcur[j], c) : 0;
        hist[j] = base;             // reuse as cursor (global offset in bucket stream)
    }
    __syncthreads();
    for (int i = lo + t; i < hi; i += 1024) {
        int s, d;
        if (i < EE) { s = ei[i]; d = ei[EE + i]; }
        else        { s = d = i - EE; }          // self loops
        int b   = d / NPB;
        int pos = atomicAdd(&hist[b], 1);
        if (pos < CAP) tmp[b * CAP + pos] = (s << 6) | (d - b * NPB);
    }
}

// exclusive scan of 1024 bucket sizes (one block)
__global__ __launch_bounds__(1024) void k_bscan(const int* __restrict__ bcur,
                                                int* __restrict__ bstart,
                                                int* __restrict__ off) {
    __shared__ int s[NBK];
    int t = threadIdx.x;
    int v0 = bcur[t];
    s[t] = v0;
    __syncthreads();
    for (int d = 1; d < NBK; d <<= 1) {
        int v = (t >= d) ? s[t - d] : 0;
        __syncthreads();
        s[t] += v;
        __syncthreads();
    }
    bstart[t] = s[t] - v0;     // exclusive
    if (t == 0) off[NN] = ETOT;
}

// pass 2: one block per bucket — stage in LDS, count, scan, scatter; also emits
// per-edge dst id (dstid) for the edge-parallel weight kernel.
__global__ __launch_bounds__(256) void k_bucket2csr(const int* __restrict__ tmp,
                                                    const int* __restrict__ bcur,
                                                    const int* __restrict__ bstart,
                                                    int* __restrict__ off,
                                                    int* __restrict__ csr,
                                                    int* __restrict__ dstid) {
    __shared__ int sE[CAP];
    __shared__ int lcnt[NPB];
    __shared__ int loff[NPB];
    int b = blockIdx.x, t = threadIdx.x;
    int n0    = b * NPB;
    int bsize = min(bcur[b], CAP);
    int base  = bstart[b];
    if (t < NPB) lcnt[t] = 0;
    for (int i = t; i < bsize; i += 256) sE[i] = tmp[b * CAP + i];
    __syncthreads();
    for (int i = t; i < bsize; i += 256) atomicAdd(&lcnt[sE[i] & 63], 1);
    __syncthreads();
    if (t == 0) {
        int run = 0;
        for (int j = 0; j < NPB; ++j) { loff[j] = run; run += lcnt[j]; }
    }
    __syncthreads();
    if (t < NPB) {
        if (n0 + t < NN) off[n0 + t] = base + loff[t];
        lcnt[t] = loff[t];            // reuse as cursor
    }
    __syncthreads();
    for (int i = t; i < bsize; i += 256) {
        int v   = sE[i];
        int d   = v & 63;
        int pos = base + atomicAdd(&lcnt[d], 1);
        csr[pos]   = v >> 6;
        dstid[pos] = n0 + d;
    }
}

// ---------------- input linear: h0 = x @ w_in + b_in (8 nodes/block) ----------------

__global__ __launch_bounds__(128) void k_in(const float* __restrict__ x,
                                            const float* __restrict__ w,
                                            const float* __restrict__ b,
                                            float* __restrict__ h0) {
    __shared__ __align__(16) float xr[8][INF_];
    int n0 = blockIdx.x * 8, t = threadIdx.x;
    for (int i = t; i < 8 * INF_; i += 128) xr[i >> 6][i & 63] = x[n0 * INF_ + i];
    __syncthreads();
    float acc[8];
    float bb = b[t];
    #pragma unroll
    for (int r = 0; r < 8; ++r) acc[r] = bb;
    const float4* h4 = reinterpret_cast<const float4*>(&xr[0][0]);
    for (int k4 = 0; k4 < INF_ / 4; ++k4) {
        int k = k4 * 4;
        float w0 = w[(k + 0) * HID + t];
        float w1 = w[(k + 1) * HID + t];
        float w2 = w[(k + 2) * HID + t];
        float w3 = w[(k + 3) * HID + t];
        #pragma unroll
        for (int r = 0; r < 8; ++r) {
            float4 hv = h4[r * (INF_ / 4) + k4];
            acc[r] = fmaf(hv.x, w0, fmaf(hv.y, w1, fmaf(hv.z, w2, fmaf(hv.w, w3, acc[r]))));
        }
    }
    #pragma unroll
    for (int r = 0; r < 8; ++r) h0[(n0 + r) * HID + t] = acc[r];
}

// ------- fused LN + GELU + hW = h @ W (bf16 out) + head scores (8 nodes/block) -------

__global__ __launch_bounds__(128) void k_feat(const float* __restrict__ hin,
                                              const float* __restrict__ g,
                                              const float* __restrict__ be,
                                              const float* __restrict__ W,
                                              const float* __restrict__ asrc,
                                              const float* __restrict__ adst,
                                              __hip_bfloat16* __restrict__ hWb,
                                              float* __restrict__ esrc,
                                              float* __restrict__ edst) {
    __shared__ __align__(16) float hrow[8][HID];
    int n0 = blockIdx.x * 8, t = threadIdx.x;
    for (int i = t; i < 8 * HID; i += 128) hrow[i >> 7][i & 127] = hin[n0 * HID + i];
    __syncthreads();

    int node = t >> 4, lane = t & 15;
    float s1 = 0.f, s2 = 0.f;
    #pragma unroll
    for (int j = 0; j < 8; ++j) {
        float v = hrow[node][lane + 16 * j];
        s1 += v; s2 += v * v;
    }
    #pragma unroll
    for (int m = 1; m < 16; m <<= 1) {
        s1 += __shfl_xor(s1, m, 16);
        s2 += __shfl_xor(s2, m, 16);
    }
    float mu  = s1 * (1.0f / 128.0f);
    float var = s2 * (1.0f / 128.0f) - mu * mu;
    float rs  = rsqrtf(var + 1e-5f);
    #pragma unroll
    for (int j = 0; j < 8; ++j) {
        int col = lane + 16 * j;
        float v = hrow[node][col];
        float y = (v - mu) * rs * g[col] + be[col];
        hrow[node][col] = gelu_tanh(y);   // same thread wrote/reads this slot
    }
    __syncthreads();

    float acc[8] = {0.f, 0.f, 0.f, 0.f, 0.f, 0.f, 0.f, 0.f};
    const float4* h4 = reinterpret_cast<const float4*>(&hrow[0][0]);
    for (int k4 = 0; k4 < HID / 4; ++k4) {
        int k = k4 * 4;
        float w0 = W[(k + 0) * HID + t];
        float w1 = W[(k + 1) * HID + t];
        float w2 = W[(k + 2) * HID + t];
        float w3 = W[(k + 3) * HID + t];
        #pragma unroll
        for (int r = 0; r < 8; ++r) {
            float4 hv = h4[r * (HID / 4) + k4];
            acc[r] = fmaf(hv.x, w0, fmaf(hv.y, w1, fmaf(hv.z, w2, fmaf(hv.w, w3, acc[r]))));
        }
    }
    float as = asrc[t], ad = adst[t];
    #pragma unroll
    for (int r = 0; r < 8; ++r) {
        hWb[(n0 + r) * HID + t] = __float2bfloat16(acc[r]);
        float v1 = acc[r] * as, v2 = acc[r] * ad;
        #pragma unroll
        for (int m = 1; m < 32; m <<= 1) {
            v1 += __shfl_xor(v1, m, 32);
            v2 += __shfl_xor(v2, m, 32);
        }
        if ((t & 31) == 0) {
            esrc[(n0 + r) * 4 + (t >> 5)] = v1;
            edst[(n0 + r) * 4 + (t >> 5)] = v2;
        }
    }
}

// ------- edge-parallel attention weights: wexp[e][h] = exp(lrelu(esrc+edst)) (bf16) -------

__global__ __launch_bounds__(256) void k_edgew(const int* __restrict__ csr,
                                               const int* __restrict__ dstid,
                                               const float* __restrict__ esrc,
                                               const float* __restrict__ edst,
                                               ushort* __restrict__ wexp) {
    int i = blockIdx.x * 256 + threadIdx.x;
    if (i >= ETOT) return;
    int s = csr[i], d = dstid[i];
    float4 es = reinterpret_cast<const float4*>(esrc)[s];
    float4 ed = reinterpret_cast<const float4*>(edst)[d];
    float e0 = es.x + ed.x, e1 = es.y + ed.y, e2 = es.z + ed.z, e3 = es.w + ed.w;
    // leaky_relu(x, 0.2) == max(x, 0.2x) for slope<1
    e0 = __expf(fmaxf(e0, 0.2f * e0));
    e1 = __expf(fmaxf(e1, 0.2f * e1));
    e2 = __expf(fmaxf(e2, 0.2f * e2));
    e3 = __expf(fmaxf(e3, 0.2f * e3));
    __hip_bfloat16 b0 = __float2bfloat16(e0), b1 = __float2bfloat16(e1);
    __hip_bfloat16 b2 = __float2bfloat16(e2), b3 = __float2bfloat16(e3);
    ushort4 pk;
    pk.x = *(ushort*)&b0; pk.y = *(ushort*)&b1; pk.z = *(ushort*)&b2; pk.w = *(ushort*)&b3;
    reinterpret_cast<ushort4*>(wexp)[i] = pk;
}

// ------- GAT aggregate per destination node: barrier-free gather loop -------
// 128 thr = 2 waves x 4 edge-slots x 16 lane-groups; lane group q holds cols 8q..8q+7.
// 8 edges in flight per trip; loads independent across iterations; single final barrier.

__global__ __launch_bounds__(128) void k_gat(const __hip_bfloat16* __restrict__ hWb,
                                             const ushort* __restrict__ wexp,
                                             const int* __restrict__ off,
                                             const int* __restrict__ csr,
                                             const float* __restrict__ bg,
                                             float* __restrict__ out) {
    __shared__ float redA[16][8];
    __shared__ float redD[16];
    int n = blockIdx.x, t = threadIdx.x;
    int wv = t >> 6, l = t & 63;
    int slot = l >> 4;          // lane bits 4-5 = edge slot
    int q    = l & 15;          // col group: cols 8q..8q+7
    int hq   = q >> 2;          // head of those cols
    int o0 = off[n], o1 = off[n + 1];
    int deg = o1 - o0;
    const uint4* hw4 = reinterpret_cast<const uint4*>(hWb);
    float acc[8] = {0.f, 0.f, 0.f, 0.f, 0.f, 0.f, 0.f, 0.f};
    float dsum = 0.f;
    int nIter = (deg + 7) >> 3;
    int e = o0 + wv * 4 + slot;
    for (int it = 0; it < nIter; ++it, e += 8) {
        int  ec    = min(e, ETOT - 1);
        bool valid = e < o1;
        int  src   = csr[ec];
        ushort ub  = wexp[ec * 4 + hq];
        float w = __uint_as_float(((unsigned)ub) << 16);
        w = valid ? w : 0.f;
        uint4 r = hw4[src * 16 + q];
        acc[0] = fmaf(w, __uint_as_float(r.x << 16),          acc[0]);
        acc[1] = fmaf(w, __uint_as_float(r.x & 0xffff0000u),  acc[1]);
        acc[2] = fmaf(w, __uint_as_float(r.y << 16),          acc[2]);
        acc[3] = fmaf(w, __uint_as_float(r.y & 0xffff0000u),  acc[3]);
        acc[4] = fmaf(w, __uint_as_float(r.z << 16),          acc[4]);
        acc[5] = fmaf(w, __uint_as_float(r.z & 0xffff0000u),  acc[5]);
        acc[6] = fmaf(w, __uint_as_float(r.w << 16),          acc[6]);
        acc[7] = fmaf(w, __uint_as_float(r.w & 0xffff0000u),  acc[7]);
        dsum += w;
    }
    // reduce across the 4 edge slots (lane bits 4 and 5)
    #pragma unroll
    for (int m = 16; m <= 32; m <<= 1) {
        #pragma unroll
        for (int j = 0; j < 8; ++j) acc[j] += __shfl_xor(acc[j], m, 64);
        dsum += __shfl_xor(dsum, m, 64);
    }
    if (wv == 1 && l < 16) {
        #pragma unroll
        for (int j = 0; j < 8; ++j) redA[l][j] = acc[j];
        redD[l] = dsum;
    }
    __syncthreads();
    if (wv == 0 && l < 16) {
        float inv = 1.0f / (dsum + redD[l]);
        float4 r0, r1;
        r0.x = (acc[0] + redA[l][0]) * inv + bg[l * 8 + 0];
        r0.y = (acc[1] + redA[l][1]) * inv + bg[l * 8 + 1];
        r0.z = (acc[2] + redA[l][2]) * inv + bg[l * 8 + 2];
        r0.w = (acc[3] + redA[l][3]) * inv + bg[l * 8 + 3];
        r1.x = (acc[4] + redA[l][4]) * inv + bg[l * 8 + 4];
        r1.y = (acc[5] + redA[l][5]) * inv + bg[l * 8 + 5];
        r1.z = (acc[6] + redA[l][6]) * inv + bg[l * 8 + 6];
        r1.w = (acc[7] + redA[l][7]) * inv + bg[l * 8 + 7];
        float4* op = reinterpret_cast<float4*>(out + n * HID + l * 8);
        op[0] = r0; op[1] = r1;
    }
}

// ---------------- output linear (8 nodes/block) ----------------

__global__ __launch_bounds__(64) void k_out(const float* __restrict__ h,
                                            const float* __restrict__ w,
                                            const float* __restrict__ b,
                                            float* __restrict__ out) {
    __shared__ __align__(16) float hr[8][HID];
    int n0 = blockIdx.x * 8, t = threadIdx.x;
    for (int i = t; i < 8 * HID; i += 64) hr[i >> 7][i & 127] = h[n0 * HID + i];
    __syncthreads();
    float acc[8];
    float bb = b[t];
    #pragma unroll
    for (int r = 0; r < 8; ++r) acc[r] = bb;
    const float4* h4 = reinterpret_cast<const float4*>(&hr[0][0]);
    for (int k4 = 0; k4 < HID / 4; ++k4) {
        int k = k4 * 4;
        float w0 = w[(k + 0) * OUTF + t];
        float w1 = w[(k + 1) * OUTF + t];
        float w2 = w[(k + 2) * OUTF + t];
        float w3 = w[(k + 3) * OUTF + t];
        #pragma unroll
        for (int r = 0; r < 8; ++r) {
            float4 hv = h4[r * (HID / 4) + k4];
            acc[r] = fmaf(hv.x, w0, fmaf(hv.y, w1, fmaf(hv.z, w2, fmaf(hv.w, w3, acc[r]))));
        }
    }
    #pragma unroll
    for (int r = 0; r < 8; ++r) out[(n0 + r) * OUTF + t] = acc[r];
}

extern "C" void kernel_launch(void* const* d_in, const int* in_sizes, int n_in,
                              void* d_out, int out_size, void* d_ws, size_t ws_size,
                              hipStream_t stream) {
    const float* x    = (const float*)d_in[0];
    const int*   ei   = (const int*)  d_in[1];   // [2, E] int32
    const float* w_in = (const float*)d_in[2];
    const float* b_in = (const float*)d_in[3];
    const float* g1   = (const float*)d_in[4];
    const float* be1  = (const float*)d_in[5];
    const float* W1   = (const float*)d_in[6];
    const float* as1  = (const float*)d_in[7];
    const float* ad1  = (const float*)d_in[8];
    const float* bg1  = (const float*)d_in[9];
    const float* g2   = (const float*)d_in[10];
    const float* be2  = (const float*)d_in[11];
    const float* W2   = (const float*)d_in[12];
    const float* as2  = (const float*)d_in[13];
    const float* ad2  = (const float*)d_in[14];
    const float* bg2  = (const float*)d_in[15];
    const float* w_o  = (const float*)d_in[16];
    const float* b_o  = (const float*)d_in[17];
    float* out = (float*)d_out;

    char* p = (char*)d_ws;
    auto take = [&](size_t bytes) {
        void* r = p;
        p += (bytes + 255) & ~(size_t)255;
        return r;
    };
    float*          h0    = (float*)take((size_t)NN * HID * 4);
    float*          gout  = (float*)take((size_t)NN * HID * 4);
    __hip_bfloat16* hWb   = (__hip_bfloat16*)take((size_t)NN * HID * 2);
    float*          esrc  = (float*)take((size_t)NN * 4 * 4);
    float*          edst  = (float*)take((size_t)NN * 4 * 4);
    int*            off   = (int*)take((size_t)(NN + 1) * 4);
    int*            csr   = (int*)take((size_t)ETOT * 4);
    int*            dstid = (int*)take((size_t)ETOT * 4);
    // wexp (ETOT ushort4 = 13.2 MB) aliases tmp (12.6 MB): build finishes before use
    size_t ovl = (size_t)ETOT * 8;
    size_t tsz = (size_t)NBK * CAP * 4;
    ushort*         wexp  = (ushort*)take(ovl > tsz ? ovl : tsz);
    int*            tmp   = (int*)wexp;
    int*            bcur  = (int*)take((size_t)NBK * 4);
    int*            bstart= (int*)take((size_t)NBK * 4);

    k_zero      <<<(NBK + 255) / 256, 256, 0, stream>>>(bcur);
    k_bucket    <<<ABLK, 1024, 0, stream>>>(ei, bcur, tmp);
    k_bscan     <<<1, NBK, 0, stream>>>(bcur, bstart, off);
    k_bucket2csr<<<NBK, 256, 0, stream>>>(tmp, bcur, bstart, off, csr, dstid);

    k_in   <<<NN / 8, 128, 0, stream>>>(x, w_in, b_in, h0);
    k_feat <<<NN / 8, 128, 0, stream>>>(h0,   g1, be1, W1, as1, ad1, hWb, esrc, edst);
    k_edgew<<<(ETOT + 255) / 256, 256, 0, stream>>>(csr, dstid, esrc, edst, wexp);
    k_gat  <<<NN, 128, 0, stream>>>(hWb, wexp, off, csr, bg1, gout);
    k_feat <<<NN / 8, 128, 0, stream>>>(gout, g2, be2, W2, as2, ad2, hWb, esrc, edst);
    k_edgew<<<(ETOT + 255) / 256, 256, 0, stream>>>(csr, dstid, esrc, edst, wexp);
    k_gat  <<<NN, 128, 0, stream>>>(hWb, wexp, off, csr, bg2, h0);
    k_out  <<<NN / 8, 64, 0, stream>>>(h0, w_o, b_o, out);
}